// Round 2
// baseline (289.648 us; speedup 1.0000x reference)
//
#include <hip/hip_runtime.h>
#include <hip/hip_cooperative_groups.h>
#include <cstddef>

namespace cg = cooperative_groups;

#define BATCH 64
#define HW 512
#define RVAL (1.0f / 512.0f)   // r = c = 1/512, exact in fp32
#define EPS_ 1e-6f
#define MAXIT 100
#define NBLK 256
#define NTHR 512

// Register-resident Sinkhorn: P = diag(u) * exp(-M) * diag(v).
// Each block owns a 128-row slab of one batch; K = exp(-M) lives entirely in
// VGPRs (float4 k4[32] per thread = 16 rows x 8 cols). Iterations touch no
// K memory; only a 2 KB column-partial exchange between the 4 blocks of a
// batch per iteration, synced by a per-batch device-scope barrier.
__global__ __launch_bounds__(NTHR, 2)
void sinkhorn_reg(const float* __restrict__ M, float* __restrict__ P,
                  float* __restrict__ colpart, int* __restrict__ bar) {
    const int tid = threadIdx.x;
    const int bid = blockIdx.x;
    const int b   = bid >> 2;      // batch index
    const int blk = bid & 3;       // 128-row slab within batch
    const int w   = tid >> 6;      // wave 0..7
    const int l   = tid & 63;      // lane 0..63

    cg::grid_group grid = cg::this_grid();

    __shared__ float v_lds[HW];        // current v (replicated per block)
    __shared__ float part[8][HW];      // per-wave column partials

    // this thread's 16 rows start here (global flattened row index)
    const int grow0 = b * HW + blk * 128 + w * 16;
    const float* Mrow = M + (size_t)grow0 * HW + l * 8;

    // ---- one-time load: K = exp(-M) into registers (static indexing only) --
    float4 k4[32];
#pragma unroll
    for (int rr = 0; rr < 16; ++rr) {
        const float4* src = (const float4*)(Mrow + (size_t)rr * HW);
        float4 m0 = src[0], m1 = src[1];
        float4 a, c;
        a.x = __expf(-m0.x); a.y = __expf(-m0.y);
        a.z = __expf(-m0.z); a.w = __expf(-m0.w);
        c.x = __expf(-m1.x); c.y = __expf(-m1.y);
        c.z = __expf(-m1.z); c.w = __expf(-m1.w);
        k4[rr * 2] = a; k4[rr * 2 + 1] = c;
    }

    v_lds[tid] = 1.0f;
    __syncthreads();

    float u_loc[16];
    for (int it = 0; it < MAXIT; ++it) {
        // ---- phase A: u_i = r / (K v)_i  (row sums, in-register) ----
        float4 v0 = *(const float4*)&v_lds[l * 8];
        float4 v1 = *(const float4*)&v_lds[l * 8 + 4];
#pragma unroll
        for (int rr = 0; rr < 16; ++rr) {
            float4 a = k4[rr * 2], c = k4[rr * 2 + 1];
            float s = a.x * v0.x + a.y * v0.y + a.z * v0.z + a.w * v0.w
                    + c.x * v1.x + c.y * v1.y + c.z * v1.z + c.w * v1.w;
#pragma unroll
            for (int off = 32; off >= 1; off >>= 1) s += __shfl_xor(s, off, 64);
            u_loc[rr] = RVAL / s;      // replicated across the wave
        }

        // ---- phase B: column partials over this wave's 16 rows ----
        float4 p0 = make_float4(0.f, 0.f, 0.f, 0.f);
        float4 p1 = make_float4(0.f, 0.f, 0.f, 0.f);
#pragma unroll
        for (int rr = 0; rr < 16; ++rr) {
            float u = u_loc[rr];
            float4 a = k4[rr * 2], c = k4[rr * 2 + 1];
            p0.x += u * a.x; p0.y += u * a.y; p0.z += u * a.z; p0.w += u * a.w;
            p1.x += u * c.x; p1.y += u * c.y; p1.z += u * c.z; p1.w += u * c.w;
        }
        *(float4*)&part[w][l * 8]     = p0;
        *(float4*)&part[w][l * 8 + 4] = p1;
        __syncthreads();
        float t = 0.f;
#pragma unroll
        for (int ww = 0; ww < 8; ++ww) t += part[ww][tid];

        // ---- exchange 512-col partials among the 4 blocks of this batch ----
        const int par = it & 1;   // double-buffered slots (see barrier proof)
        float* slot = colpart + ((size_t)par * BATCH * 4 + (size_t)b * 4 + blk) * HW;
        slot[tid] = t;
        __threadfence();                       // agent-scope: publish slot
        __syncthreads();
        int* bslot = bar + b * MAXIT + it;
        if (tid == 0) {
            __hip_atomic_fetch_add(bslot, 1, __ATOMIC_RELEASE,
                                   __HIP_MEMORY_SCOPE_AGENT);
            while (__hip_atomic_load(bslot, __ATOMIC_ACQUIRE,
                                     __HIP_MEMORY_SCOPE_AGENT) < 4)
                __builtin_amdgcn_s_sleep(2);
        }
        __syncthreads();

        float tt = 0.f;
        const float* base = colpart + ((size_t)par * BATCH * 4 + (size_t)b * 4) * HW;
#pragma unroll
        for (int bb = 0; bb < 4; ++bb)
            tt += __hip_atomic_load(base + bb * HW + tid, __ATOMIC_ACQUIRE,
                                    __HIP_MEMORY_SCOPE_AGENT);

        // per-batch convergence (identical t on all 4 blocks -> lockstep).
        float vold = v_lds[tid];
        int viol = fabsf(vold * tt - RVAL) > EPS_;
        int any = __syncthreads_or(viol);
        if (!any) break;           // keep row-normalized state (u_loc, v old)
        v_lds[tid] = RVAL / tt;    // col-normalize accepted
        __syncthreads();
    }

    // All P stores strictly after a grid-wide sync so the d_out-tail scratch
    // fallback can never be clobbered while another batch still iterates.
    grid.sync();

    // ---- final: P = diag(u) K diag(v), straight from registers ----
    float4 v0 = *(const float4*)&v_lds[l * 8];
    float4 v1 = *(const float4*)&v_lds[l * 8 + 4];
    float* Prow = P + (size_t)grow0 * HW + l * 8;
#pragma unroll
    for (int rr = 0; rr < 16; ++rr) {
        float u = u_loc[rr];
        float4 a = k4[rr * 2], c = k4[rr * 2 + 1];
        float4 o0, o1;
        o0.x = u * a.x * v0.x; o0.y = u * a.y * v0.y;
        o0.z = u * a.z * v0.z; o0.w = u * a.w * v0.w;
        o1.x = u * c.x * v1.x; o1.y = u * c.y * v1.y;
        o1.z = u * c.z * v1.z; o1.w = u * c.w * v1.w;
        float4* dst = (float4*)(Prow + (size_t)rr * HW);
        dst[0] = o0; dst[1] = o1;
    }
}

extern "C" void kernel_launch(void* const* d_in, const int* in_sizes, int n_in,
                              void* d_out, int out_size, void* d_ws, size_t ws_size,
                              hipStream_t stream) {
    const float* M = (const float*)d_in[0];
    float* P = (float*)d_out;

    const size_t CP_FLOATS = (size_t)2 * BATCH * 4 * HW;   // double-buffered partials
    const size_t BAR_INTS  = (size_t)BATCH * MAXIT;
    const size_t NEED = CP_FLOATS * sizeof(float) + BAR_INTS * sizeof(int);

    char* scratch;
    if (ws_size >= NEED) {
        scratch = (char*)d_ws;
    } else {
        // tail of d_out; safe because every P store happens after grid.sync()
        scratch = (char*)d_out + (size_t)out_size * sizeof(float) - NEED;
    }
    float* colpart = (float*)scratch;
    int*   bar     = (int*)(scratch + CP_FLOATS * sizeof(float));

    hipMemsetAsync(bar, 0, BAR_INTS * sizeof(int), stream);

    void* args[] = { (void*)&M, (void*)&P, (void*)&colpart, (void*)&bar };
    hipLaunchCooperativeKernel((const void*)sinkhorn_reg, dim3(NBLK), dim3(NTHR),
                               args, 0, stream);
}